// Round 6
// baseline (169.640 us; speedup 1.0000x reference)
//
#include <hip/hip_runtime.h>

#define BB 4
#define NN 256
#define DMM 128
#define DEE 8
#define HH 8
#define DD 16
#define LAYERS 2
#define SCALE 0.25f
#define PS 260               // padded LDS stride (floats)
#define SS (BB*NN*DMM)       // 131072 floats per per-layer buffer

struct Params {
  const float *nodes, *edges, *adjacency;
  const float *Wq, *bq, *Wk, *bk, *Wv, *bv, *We, *be, *Wres, *bres, *Wgate, *lng, *lnb;
  const float *src;
  float *q, *k, *v, *res;   // layer-0 bases for k_proj/k_mid; layer-1 bases for final k_attn
  float *out;
  int layer;
};

// ---------------- D1: q,k,v,res = src @ W + b (layer 0); 512 blocks x 2 rows ----------------
__global__ __launch_bounds__(256) void k_proj(Params P){
  const int t = threadIdx.x;
  const int m = t >> 6;
  const int cp = t & 63;
  const int row0 = blockIdx.x * 2;
  const int l = P.layer;
  const float *W, *bia; float* dst;
  if (m==0){ W = P.Wq + l*DMM*DMM; bia = P.bq + l*DMM; dst = P.q; }
  else if (m==1){ W = P.Wk + l*DMM*DMM; bia = P.bk + l*DMM; dst = P.k; }
  else if (m==2){ W = P.Wv + l*DMM*DMM; bia = P.bv + l*DMM; dst = P.v; }
  else { W = P.Wres + l*DMM*DMM; bia = P.bres + l*DMM; dst = P.res; }
  const float2 bv2 = *(const float2*)(bia + 2*cp);
  float a00=bv2.x, a01=bv2.y, a10=bv2.x, a11=bv2.y;
  const float2* W2 = (const float2*)W;
  const float* xr = P.src + (size_t)row0*DMM;   // wave-uniform -> scalar loads
  #pragma unroll 8
  for (int kk=0; kk<DMM; kk++){
    float2 w = W2[kk*64+cp];
    float x0 = xr[kk], x1 = xr[DMM+kk];
    a00 += x0*w.x; a01 += x0*w.y;
    a10 += x1*w.x; a11 += x1*w.y;
  }
  *(float2*)(dst + (size_t)row0*DMM     + 2*cp) = make_float2(a00,a01);
  *(float2*)(dst + (size_t)(row0+1)*DMM + 2*cp) = make_float2(a10,a11);
}

// ---------------- D2: attn(l=0) for 2 CONCURRENT rows + proj(l=1) ----------------
// 512 blocks x 512 threads; sub-block r=t>>8 owns row row0+r through attention.
// Reads q0/k0/v0/res0 (D1 output, coherence via dispatch boundary). x1 stays in
// LDS; trailing proj writes q1/k1/v1/res1 at +SS using all 8 waves.
// NOTE: reference's mean-shift cancels exactly in _adj_softmax (exp(-m) factors
// out of numerator and denominator; s==0 rows identical) - no shift applied.
__global__ __launch_bounds__(512) void k_mid(Params P){
  const int t = threadIdx.x;
  const int r = t >> 8;            // concurrent row index
  const int u = t & 255;           // index within sub-block
  const int row0 = blockIdx.x*2;
  const int row  = row0 + r;
  const int b = row0 >> 8;         // adjacent rows -> same batch

  __shared__ float xloc[2][128];   // x1 rows (attn0 output)
  __shared__ float qs[2][128];
  __shared__ float res_s[2][128];
  __shared__ float qwe_s[2][64];
  __shared__ float qbe_s[2][8];
  __shared__ float es[2][8*PS];
  __shared__ float ps[2][8*PS];
  __shared__ float red_s[2][32];
  __shared__ float ssum_s[2][8];
  __shared__ float g_s[2][64];
  __shared__ float red_a[2][2], red_b[2][2], red_c[2][2];

  // ---- load q0/res0 rows, edge row (regs + es), adjacency ----
  if (u < 128) qs[r][u]        = P.q  [(size_t)row*DMM + u];
  else         res_s[r][u-128] = P.res[(size_t)row*DMM + (u-128)];
  const int j = u;
  float ec[8]; float adj;
  {
    const float4* er4 = (const float4*)(P.edges + ((size_t)row*NN + j)*DEE);
    float4 e0 = er4[0], e1 = er4[1];
    ec[0]=e0.x; ec[1]=e0.y; ec[2]=e0.z; ec[3]=e0.w;
    ec[4]=e1.x; ec[5]=e1.y; ec[6]=e1.z; ec[7]=e1.w;
    #pragma unroll
    for (int c=0;c<8;c++) es[r][c*PS+j] = ec[c];
    adj = P.adjacency[(size_t)row*NN + j];
  }
  __syncthreads();

  // ---- q-side edge projections (layer 0 weights), per sub-block ----
  if (u < 64){
    const int h = u>>3, c = u&7;
    const float* Wer = P.We + c*DMM + h*DD;
    float a = 0.f;
    #pragma unroll
    for (int d=0; d<DD; d++) a += qs[r][h*DD+d]*Wer[d];
    qwe_s[r][u] = a;
    if (c==0){
      const float* ber = P.be + h*DD;
      float a2=0.f;
      #pragma unroll
      for (int d=0; d<DD; d++) a2 += qs[r][h*DD+d]*ber[d];
      qbe_s[r][h] = a2;
    }
  }
  __syncthreads();

  // ---- phase 1: thread (r,j) computes p for all 8 heads ----
  {
    const float4* kr = (const float4*)(P.k + ((size_t)b*NN + j)*DMM);
    float preg[8];
    #pragma unroll
    for (int h=0; h<HH; h++){
      float4 k0=kr[h*4+0], k1=kr[h*4+1], k2=kr[h*4+2], k3=kr[h*4+3];
      const float4* q4 = (const float4*)(&qs[r][h*DD]);
      float4 qa=q4[0], qb=q4[1], qc=q4[2], qd=q4[3];
      float sim = qbe_s[r][h];
      sim += qa.x*k0.x + qa.y*k0.y + qa.z*k0.z + qa.w*k0.w;
      sim += qb.x*k1.x + qb.y*k1.y + qb.z*k1.z + qb.w*k1.w;
      sim += qc.x*k2.x + qc.y*k2.y + qc.z*k2.z + qc.w*k2.w;
      sim += qd.x*k3.x + qd.y*k3.y + qd.z*k3.z + qd.w*k3.w;
      const float4* qw4 = (const float4*)(&qwe_s[r][h*8]);
      float4 wA=qw4[0], wB=qw4[1];
      sim += ec[0]*wA.x + ec[1]*wA.y + ec[2]*wA.z + ec[3]*wA.w;
      sim += ec[4]*wB.x + ec[5]*wB.y + ec[6]*wB.z + ec[7]*wB.w;
      sim *= SCALE;
      float p = __expf(sim)*adj;
      preg[h]=p; ps[r][h*PS+j]=p;
    }
    #pragma unroll
    for (int h=0; h<HH; h++){
      float v = preg[h];
      #pragma unroll
      for (int off=32; off; off>>=1) v += __shfl_xor(v, off, 64);
      if ((u&63)==0) red_s[r][(u>>6)*8+h] = v;
    }
  }
  __syncthreads();

  // ---- phase 2: pv (u<128), g (128<=u<192), ssum (u>=248) ----
  float pv = 0.f;
  if (u < 128){
    const int h = u>>4;
    const float* vcol = P.v + (size_t)b*NN*DMM + u;     // h*DD+d == u
    const float4* pr = (const float4*)(&ps[r][h*PS]);
    #pragma unroll 4
    for (int jq=0; jq<64; jq++){
      float4 pp = pr[jq];
      const float* vv = vcol + jq*4*DMM;
      pv += pp.x*vv[0] + pp.y*vv[DMM] + pp.z*vv[2*DMM] + pp.w*vv[3*DMM];
    }
  } else if (u < 192){
    const int h=(u-128)>>3, c=(u-128)&7;
    const float4* pr = (const float4*)(&ps[r][h*PS]);
    const float4* er = (const float4*)(&es[r][c*PS]);
    float g=0.f;
    #pragma unroll 4
    for (int jq=0; jq<64; jq++){
      float4 pp=pr[jq], ee=er[jq];
      g += pp.x*ee.x + pp.y*ee.y + pp.z*ee.z + pp.w*ee.w;
    }
    g_s[r][h*8+c]=g;
  } else if (u >= 248){
    const int h=u-248;
    ssum_s[r][h] = red_s[r][h]+red_s[r][8+h]+red_s[r][16+h]+red_s[r][24+h];
  }
  __syncthreads();

  // ---- phase 3: assemble out, gate reduction (layer 0 weights) ----
  float o=0.f, rr=0.f;
  if (u<128){
    const int h = u>>4;
    const float* Wec = P.We + u;
    float eacc=0.f;
    #pragma unroll
    for (int c=0;c<8;c++) eacc += Wec[c*DMM]*g_s[r][h*8+c];
    const float ssum = ssum_s[r][h];
    const float denom = (ssum==0.f)?1.f:ssum;
    const float bev = P.be[u];
    o = (pv + eacc + ssum*bev)/denom;
    rr = res_s[r][u];
    const float* Wg = P.Wgate;
    float contrib = o*Wg[u] + rr*Wg[DMM+u] + (o-rr)*Wg[2*DMM+u];
    #pragma unroll
    for (int off=32; off; off>>=1) contrib += __shfl_xor(contrib, off, 64);
    if ((u&63)==0) red_a[r][u>>6]=contrib;
  }
  __syncthreads();

  float y=0.f;
  if (u<128){
    const float gs = red_a[r][0]+red_a[r][1];
    const float gate = 1.f/(1.f+__expf(-gs));
    y = o*gate + rr*(1.f-gate);
    float s1=y, s2=y*y;
    #pragma unroll
    for (int off=32; off; off>>=1){ s1+=__shfl_xor(s1,off,64); s2+=__shfl_xor(s2,off,64); }
    if ((u&63)==0){ red_b[r][u>>6]=s1; red_c[r][u>>6]=s2; }
  }
  __syncthreads();

  if (u<128){
    const float mu  = (red_b[r][0]+red_b[r][1])*(1.f/128.f);
    const float var = (red_c[r][0]+red_c[r][1])*(1.f/128.f) - mu*mu;
    const float inv = rsqrtf(var+1e-5f);
    float yn = (y-mu)*inv*P.lng[u] + P.lnb[u];
    xloc[r][u] = fmaxf(yn, 0.f);
  }
  __syncthreads();

  // ---- proj(l=1) for both rows: wave w -> matrix w&3, row w>>2 ----
  {
    const int w = t>>6, m = w&3, ri = w>>2, cp = t&63;
    const float *W, *bia; float* dst;
    if (m==0){ W=P.Wq+DMM*DMM;   bia=P.bq+DMM;   dst=P.q;   }
    else if (m==1){ W=P.Wk+DMM*DMM;   bia=P.bk+DMM;   dst=P.k;   }
    else if (m==2){ W=P.Wv+DMM*DMM;   bia=P.bv+DMM;   dst=P.v;   }
    else          { W=P.Wres+DMM*DMM; bia=P.bres+DMM; dst=P.res; }
    const float2 bv2 = *(const float2*)(bia+2*cp);
    float a0=bv2.x, a1=bv2.y;
    const float2* W2 = (const float2*)W;
    const float* xr = xloc[ri];
    #pragma unroll 8
    for (int kk=0; kk<DMM; kk++){
      float2 w2 = W2[kk*64+cp];
      float xv = xr[kk];
      a0 += xv*w2.x; a1 += xv*w2.y;
    }
    *(float2*)(dst + SS + (size_t)(row0+ri)*DMM + 2*cp) = make_float2(a0,a1);
  }
}

// ---------------- D3: attn(l=1) -> out (proven R1 kernel) ----------------
__global__ __launch_bounds__(256) void k_attn(Params P){
  const int t = threadIdx.x;
  const int b = blockIdx.x >> 8;
  const int i = blockIdx.x & 255;
  const int l = P.layer;

  __shared__ float qs[128];
  __shared__ float qwe_s[64];
  __shared__ float qbe_s[8];
  __shared__ float es[8*PS];
  __shared__ float ps[8*PS];
  __shared__ float red_s[32];
  __shared__ float ssum_s[8];
  __shared__ float g_s[64];
  __shared__ float res_s[128];
  __shared__ float red_a[2], red_b[2], red_c[2];

  if (t < 128) qs[t] = P.q[(b*NN+i)*DMM + t];
  __syncthreads();
  if (t < 64){
    const int h = t>>3, c = t&7;
    const float* Wer = P.We + l*DEE*DMM + c*DMM + h*DD;
    float a = 0.f;
    #pragma unroll
    for (int d=0; d<DD; d++) a += qs[h*DD+d]*Wer[d];
    qwe_s[t] = a;
    if (c==0){
      const float* ber = P.be + l*DMM + h*DD;
      float a2 = 0.f;
      #pragma unroll
      for (int d=0; d<DD; d++) a2 += qs[h*DD+d]*ber[d];
      qbe_s[h] = a2;
    }
  }
  __syncthreads();

  {
    const int j = t;
    const float4* er4 = (const float4*)(P.edges + ((size_t)(b*NN+i)*NN + j)*DEE);
    float4 e0 = er4[0], e1 = er4[1];
    float ec[8] = {e0.x,e0.y,e0.z,e0.w, e1.x,e1.y,e1.z,e1.w};
    #pragma unroll
    for (int c=0;c<8;c++) es[c*PS+j] = ec[c];
    const float adj = P.adjacency[(size_t)(b*NN+i)*NN + j];
    const float4* kr = (const float4*)(P.k + (b*NN+j)*DMM);
    const float* qg = P.q + (b*NN+i)*DMM;
    float preg[8];
    #pragma unroll
    for (int h=0; h<HH; h++){
      float4 k0 = kr[h*4+0], k1 = kr[h*4+1], k2 = kr[h*4+2], k3 = kr[h*4+3];
      const float* qh = qg + h*DD;
      float sim = qbe_s[h];
      sim += qh[0]*k0.x + qh[1]*k0.y + qh[2]*k0.z + qh[3]*k0.w;
      sim += qh[4]*k1.x + qh[5]*k1.y + qh[6]*k1.z + qh[7]*k1.w;
      sim += qh[8]*k2.x + qh[9]*k2.y + qh[10]*k2.z + qh[11]*k2.w;
      sim += qh[12]*k3.x + qh[13]*k3.y + qh[14]*k3.z + qh[15]*k3.w;
      const float4* qw4 = (const float4*)(qwe_s + h*8);
      float4 wA = qw4[0], wB = qw4[1];
      sim += ec[0]*wA.x + ec[1]*wA.y + ec[2]*wA.z + ec[3]*wA.w;
      sim += ec[4]*wB.x + ec[5]*wB.y + ec[6]*wB.z + ec[7]*wB.w;
      sim *= SCALE;
      float p = __expf(sim) * adj;
      preg[h] = p;
      ps[h*PS+j] = p;
    }
    #pragma unroll
    for (int h=0; h<HH; h++){
      float v = preg[h];
      #pragma unroll
      for (int off=32; off; off>>=1) v += __shfl_xor(v, off, 64);
      if ((t&63)==0) red_s[(t>>6)*8 + h] = v;
    }
  }
  __syncthreads();

  float pv = 0.f;
  if (t < 128){
    const int h = t>>4;
    const float* vcol = P.v + b*NN*DMM + t;
    const float4* pr = (const float4*)(ps + h*PS);
    #pragma unroll 4
    for (int jq=0; jq<64; jq++){
      float4 pp = pr[jq];
      const float* vv = vcol + jq*4*DMM;
      pv += pp.x*vv[0] + pp.y*vv[DMM] + pp.z*vv[2*DMM] + pp.w*vv[3*DMM];
    }
  } else if (t < 192){
    const int h = (t-128)>>3, c = (t-128)&7;
    const float4* pr = (const float4*)(ps + h*PS);
    const float4* er = (const float4*)(es + c*PS);
    float g = 0.f;
    #pragma unroll 4
    for (int jq=0; jq<64; jq++){
      float4 pp = pr[jq], ee = er[jq];
      g += pp.x*ee.x + pp.y*ee.y + pp.z*ee.z + pp.w*ee.w;
    }
    g_s[h*8+c] = g;
  } else {
    const int u = t - 192;
    const float2 rv = *(const float2*)(P.res + (b*NN+i)*DMM + 2*u);
    res_s[2*u] = rv.x; res_s[2*u+1] = rv.y;
    if (t >= 248){
      const int h = t - 248;
      ssum_s[h] = red_s[h] + red_s[8+h] + red_s[16+h] + red_s[24+h];
    }
  }
  __syncthreads();

  float o = 0.f, rr = 0.f;
  if (t < 128){
    const int h = t>>4;
    const float* Wec = P.We + l*DEE*DMM + t;
    float eacc = 0.f;
    #pragma unroll
    for (int c=0;c<8;c++) eacc += Wec[c*DMM] * g_s[h*8+c];
    const float ssum = ssum_s[h];
    const float denom = (ssum==0.f) ? 1.f : ssum;
    const float bev = P.be[l*DMM + t];
    o = (pv + eacc + ssum*bev) / denom;
    rr = res_s[t];
    const float* Wg = P.Wgate + l*3*DMM;
    float contrib = o*Wg[t] + rr*Wg[DMM+t] + (o-rr)*Wg[2*DMM+t];
    #pragma unroll
    for (int off=32; off; off>>=1) contrib += __shfl_xor(contrib, off, 64);
    if ((t&63)==0) red_a[t>>6] = contrib;
  }
  __syncthreads();

  float y = 0.f;
  if (t < 128){
    const float gs = red_a[0] + red_a[1];
    const float gate = 1.f/(1.f + __expf(-gs));
    y = o*gate + rr*(1.f-gate);
    float s1 = y, s2 = y*y;
    #pragma unroll
    for (int off=32; off; off>>=1){ s1 += __shfl_xor(s1, off, 64); s2 += __shfl_xor(s2, off, 64); }
    if ((t&63)==0){ red_b[t>>6] = s1; red_c[t>>6] = s2; }
  }
  __syncthreads();

  if (t < 128){
    const float mu  = (red_b[0]+red_b[1]) * (1.f/128.f);
    const float var = (red_c[0]+red_c[1]) * (1.f/128.f) - mu*mu;
    const float inv = rsqrtf(var + 1e-5f);
    float yn = (y - mu)*inv*P.lng[l*DMM+t] + P.lnb[l*DMM+t];
    yn = fmaxf(yn, 0.f);
    P.out[(b*NN+i)*DMM + t] = yn;
  }
}

extern "C" void kernel_launch(void* const* d_in, const int* in_sizes, int n_in,
                              void* d_out, int out_size, void* d_ws, size_t ws_size,
                              hipStream_t stream) {
  Params P;
  P.nodes     = (const float*)d_in[0];
  P.edges     = (const float*)d_in[1];
  P.adjacency = (const float*)d_in[2];
  P.Wq   = (const float*)d_in[3];  P.bq   = (const float*)d_in[4];
  P.Wk   = (const float*)d_in[5];  P.bk   = (const float*)d_in[6];
  P.Wv   = (const float*)d_in[7];  P.bv   = (const float*)d_in[8];
  P.We   = (const float*)d_in[9];  P.be   = (const float*)d_in[10];
  P.Wres = (const float*)d_in[11]; P.bres = (const float*)d_in[12];
  P.Wgate= (const float*)d_in[13];
  P.lng  = (const float*)d_in[14]; P.lnb  = (const float*)d_in[15];

  float* f = (float*)d_ws;
  // per-layer buffers: [2][SS] each
  float* qbuf = f;            // q0 at +0, q1 at +SS
  float* kbuf = f + 2*SS;
  float* vbuf = f + 4*SS;
  float* rbuf = f + 6*SS;
  P.out = (float*)d_out;

  // D1: proj layer 0 (512 blocks x 2 rows)
  P.layer = 0; P.src = P.nodes;
  P.q = qbuf; P.k = kbuf; P.v = vbuf; P.res = rbuf;
  hipLaunchKernelGGL(k_proj, dim3(BB*NN/2), dim3(256), 0, stream, P);

  // D2: attn(l0, 2 concurrent rows) + proj(l1)
  hipLaunchKernelGGL(k_mid, dim3(BB*NN/2), dim3(512), 0, stream, P);

  // D3: attn(l1) -> out
  P.layer = 1;
  P.q = qbuf + SS; P.k = kbuf + SS; P.v = vbuf + SS; P.res = rbuf + SS;
  hipLaunchKernelGGL(k_attn, dim3(BB*NN), dim3(256), 0, stream, P);
}

// Round 7
// 145.415 us; speedup vs baseline: 1.1666x; 1.1666x over previous
//
#include <hip/hip_runtime.h>

#define BB 4
#define NN 256
#define DMM 128
#define DEE 8
#define HH 8
#define DD 16
#define LAYERS 2
#define SCALE 0.25f
#define PS 260               // padded LDS stride (floats)
#define SS (BB*NN*DMM)       // 131072 floats per per-layer buffer

// K is stored TRANSPOSED: kT[b][d][j] at ((b*DMM + d)*NN + j).
// Rationale (R6 counters): row-per-thread K reads are 64 cache lines per wave
// instruction (512B lane stride) -> TA-bound. Transposed reads are lane-
// consecutive -> 4 lines/instr. Scatter cost moves to the 1x write side.

struct Params {
  const float *nodes, *edges, *adjacency;
  const float *Wq, *bq, *Wk, *bk, *Wv, *bv, *We, *be, *Wres, *bres, *Wgate, *lng, *lnb;
  const float *src;
  float *q, *k, *v, *res;   // layer-0 bases for k_proj/k_mid; layer-1 bases for final k_attn
  float *out;
  int layer;
};

// ---------------- D1: q,k,v,res = src @ W + b (layer 0); 512 blocks x 2 rows ----------------
__global__ __launch_bounds__(256) void k_proj(Params P){
  const int t = threadIdx.x;
  const int m = t >> 6;
  const int cp = t & 63;
  const int row0 = blockIdx.x * 2;
  const int l = P.layer;
  const float *W, *bia; float* dst;
  if (m==0){ W = P.Wq + l*DMM*DMM; bia = P.bq + l*DMM; dst = P.q; }
  else if (m==1){ W = P.Wk + l*DMM*DMM; bia = P.bk + l*DMM; dst = P.k; }
  else if (m==2){ W = P.Wv + l*DMM*DMM; bia = P.bv + l*DMM; dst = P.v; }
  else { W = P.Wres + l*DMM*DMM; bia = P.bres + l*DMM; dst = P.res; }
  const float2 bv2 = *(const float2*)(bia + 2*cp);
  float a00=bv2.x, a01=bv2.y, a10=bv2.x, a11=bv2.y;
  const float2* W2 = (const float2*)W;
  const float* xr = P.src + (size_t)row0*DMM;   // wave-uniform -> scalar loads
  #pragma unroll 8
  for (int kk=0; kk<DMM; kk++){
    float2 w = W2[kk*64+cp];
    float x0 = xr[kk], x1 = xr[DMM+kk];
    a00 += x0*w.x; a01 += x0*w.y;
    a10 += x1*w.x; a11 += x1*w.y;
  }
  if (m==1){
    // transposed K store: kT[(b*DMM + d)*NN + i]
    const int b = row0 >> 8, i0 = row0 & 255;
    float* kT = dst + ((size_t)b*DMM + 2*cp)*NN;
    kT[i0]      = a00;  kT[NN + i0]     = a01;
    kT[i0+1]    = a10;  kT[NN + i0+1]   = a11;
  } else {
    *(float2*)(dst + (size_t)row0*DMM     + 2*cp) = make_float2(a00,a01);
    *(float2*)(dst + (size_t)(row0+1)*DMM + 2*cp) = make_float2(a10,a11);
  }
}

// ---------------- D2: attn(l=0) for 2 CONCURRENT rows + proj(l=1) ----------------
// 512 blocks x 512 threads; sub-block r=t>>8 owns row row0+r through attention.
// Reads q0/kT0/v0/res0 (D1 output, coherence via dispatch boundary). x1 stays in
// LDS; trailing proj writes q1/kT1/v1/res1 at +SS using all 8 waves.
// NOTE: reference's mean-shift cancels exactly in _adj_softmax (exp(-m) factors
// out of numerator and denominator; s==0 rows identical) - no shift applied.
__global__ __launch_bounds__(512) void k_mid(Params P){
  const int t = threadIdx.x;
  const int r = t >> 8;            // concurrent row index
  const int u = t & 255;           // index within sub-block
  const int row0 = blockIdx.x*2;
  const int row  = row0 + r;
  const int b = row0 >> 8;         // adjacent rows -> same batch

  __shared__ float xloc[2][128];   // x1 rows (attn0 output)
  __shared__ float qs[2][128];
  __shared__ float res_s[2][128];
  __shared__ float qwe_s[2][64];
  __shared__ float qbe_s[2][8];
  __shared__ float es[2][8*PS];
  __shared__ float ps[2][8*PS];
  __shared__ float red_s[2][32];
  __shared__ float ssum_s[2][8];
  __shared__ float g_s[2][64];
  __shared__ float red_a[2][2], red_b[2][2], red_c[2][2];

  // ---- load q0/res0 rows, edge row (regs + es), adjacency ----
  if (u < 128) qs[r][u]        = P.q  [(size_t)row*DMM + u];
  else         res_s[r][u-128] = P.res[(size_t)row*DMM + (u-128)];
  const int j = u;
  float ec[8]; float adj;
  {
    const float4* er4 = (const float4*)(P.edges + ((size_t)row*NN + j)*DEE);
    float4 e0 = er4[0], e1 = er4[1];
    ec[0]=e0.x; ec[1]=e0.y; ec[2]=e0.z; ec[3]=e0.w;
    ec[4]=e1.x; ec[5]=e1.y; ec[6]=e1.z; ec[7]=e1.w;
    #pragma unroll
    for (int c=0;c<8;c++) es[r][c*PS+j] = ec[c];
    adj = P.adjacency[(size_t)row*NN + j];
  }
  __syncthreads();

  // ---- q-side edge projections (layer 0 weights), per sub-block ----
  if (u < 64){
    const int h = u>>3, c = u&7;
    const float* Wer = P.We + c*DMM + h*DD;
    float a = 0.f;
    #pragma unroll
    for (int d=0; d<DD; d++) a += qs[r][h*DD+d]*Wer[d];
    qwe_s[r][u] = a;
    if (c==0){
      const float* ber = P.be + h*DD;
      float a2=0.f;
      #pragma unroll
      for (int d=0; d<DD; d++) a2 += qs[r][h*DD+d]*ber[d];
      qbe_s[r][h] = a2;
    }
  }
  __syncthreads();

  // ---- phase 1: thread (r,j) computes p for all 8 heads (K^T, coalesced) ----
  {
    const float* kTj = P.k + (size_t)b*DMM*NN + j;   // column j of K^T panel
    float preg[8];
    #pragma unroll
    for (int h=0; h<HH; h++){
      const float* kc = kTj + (size_t)(h*DD)*NN;
      float sim = qbe_s[r][h];
      #pragma unroll
      for (int d=0; d<DD; d++) sim += qs[r][h*DD+d] * kc[(size_t)d*NN];
      const float4* qw4 = (const float4*)(&qwe_s[r][h*8]);
      float4 wA=qw4[0], wB=qw4[1];
      sim += ec[0]*wA.x + ec[1]*wA.y + ec[2]*wA.z + ec[3]*wA.w;
      sim += ec[4]*wB.x + ec[5]*wB.y + ec[6]*wB.z + ec[7]*wB.w;
      sim *= SCALE;
      float p = __expf(sim)*adj;
      preg[h]=p; ps[r][h*PS+j]=p;
    }
    #pragma unroll
    for (int h=0; h<HH; h++){
      float v = preg[h];
      #pragma unroll
      for (int off=32; off; off>>=1) v += __shfl_xor(v, off, 64);
      if ((u&63)==0) red_s[r][(u>>6)*8+h] = v;
    }
  }
  __syncthreads();

  // ---- phase 2: pv (u<128), g (128<=u<192), ssum (u>=248) ----
  float pv = 0.f;
  if (u < 128){
    const int h = u>>4;
    const float* vcol = P.v + (size_t)b*NN*DMM + u;     // h*DD+d == u
    const float4* pr = (const float4*)(&ps[r][h*PS]);
    #pragma unroll 4
    for (int jq=0; jq<64; jq++){
      float4 pp = pr[jq];
      const float* vv = vcol + jq*4*DMM;
      pv += pp.x*vv[0] + pp.y*vv[DMM] + pp.z*vv[2*DMM] + pp.w*vv[3*DMM];
    }
  } else if (u < 192){
    const int h=(u-128)>>3, c=(u-128)&7;
    const float4* pr = (const float4*)(&ps[r][h*PS]);
    const float4* er = (const float4*)(&es[r][c*PS]);
    float g=0.f;
    #pragma unroll 4
    for (int jq=0; jq<64; jq++){
      float4 pp=pr[jq], ee=er[jq];
      g += pp.x*ee.x + pp.y*ee.y + pp.z*ee.z + pp.w*ee.w;
    }
    g_s[r][h*8+c]=g;
  } else if (u >= 248){
    const int h=u-248;
    ssum_s[r][h] = red_s[r][h]+red_s[r][8+h]+red_s[r][16+h]+red_s[r][24+h];
  }
  __syncthreads();

  // ---- phase 3: assemble out, gate reduction (layer 0 weights) ----
  float o=0.f, rr=0.f;
  if (u<128){
    const int h = u>>4;
    const float* Wec = P.We + u;
    float eacc=0.f;
    #pragma unroll
    for (int c=0;c<8;c++) eacc += Wec[c*DMM]*g_s[r][h*8+c];
    const float ssum = ssum_s[r][h];
    const float denom = (ssum==0.f)?1.f:ssum;
    const float bev = P.be[u];
    o = (pv + eacc + ssum*bev)/denom;
    rr = res_s[r][u];
    const float* Wg = P.Wgate;
    float contrib = o*Wg[u] + rr*Wg[DMM+u] + (o-rr)*Wg[2*DMM+u];
    #pragma unroll
    for (int off=32; off; off>>=1) contrib += __shfl_xor(contrib, off, 64);
    if ((u&63)==0) red_a[r][u>>6]=contrib;
  }
  __syncthreads();

  float y=0.f;
  if (u<128){
    const float gs = red_a[r][0]+red_a[r][1];
    const float gate = 1.f/(1.f+__expf(-gs));
    y = o*gate + rr*(1.f-gate);
    float s1=y, s2=y*y;
    #pragma unroll
    for (int off=32; off; off>>=1){ s1+=__shfl_xor(s1,off,64); s2+=__shfl_xor(s2,off,64); }
    if ((u&63)==0){ red_b[r][u>>6]=s1; red_c[r][u>>6]=s2; }
  }
  __syncthreads();

  if (u<128){
    const float mu  = (red_b[r][0]+red_b[r][1])*(1.f/128.f);
    const float var = (red_c[r][0]+red_c[r][1])*(1.f/128.f) - mu*mu;
    const float inv = rsqrtf(var+1e-5f);
    float yn = (y-mu)*inv*P.lng[u] + P.lnb[u];
    xloc[r][u] = fmaxf(yn, 0.f);
  }
  __syncthreads();

  // ---- proj(l=1) for both rows: wave w -> matrix w&3, row w>>2 ----
  {
    const int w = t>>6, m = w&3, ri = w>>2, cp = t&63;
    const float *W, *bia; float* dst;
    if (m==0){ W=P.Wq+DMM*DMM;   bia=P.bq+DMM;   dst=P.q;   }
    else if (m==1){ W=P.Wk+DMM*DMM;   bia=P.bk+DMM;   dst=P.k;   }
    else if (m==2){ W=P.Wv+DMM*DMM;   bia=P.bv+DMM;   dst=P.v;   }
    else          { W=P.Wres+DMM*DMM; bia=P.bres+DMM; dst=P.res; }
    const float2 bv2 = *(const float2*)(bia+2*cp);
    float a0=bv2.x, a1=bv2.y;
    const float2* W2 = (const float2*)W;
    const float* xr = xloc[ri];
    #pragma unroll 8
    for (int kk=0; kk<DMM; kk++){
      float2 w2 = W2[kk*64+cp];
      float xv = xr[kk];
      a0 += xv*w2.x; a1 += xv*w2.y;
    }
    const int prow = row0 + ri;
    if (m==1){
      const int pb = prow >> 8, pi = prow & 255;
      float* kT = dst + SS + ((size_t)pb*DMM + 2*cp)*NN;
      kT[pi] = a0; kT[NN + pi] = a1;
    } else {
      *(float2*)(dst + SS + (size_t)prow*DMM + 2*cp) = make_float2(a0,a1);
    }
  }
}

// ---------------- D3: attn(l=1) -> out (K^T reads) ----------------
__global__ __launch_bounds__(256) void k_attn(Params P){
  const int t = threadIdx.x;
  const int b = blockIdx.x >> 8;
  const int i = blockIdx.x & 255;
  const int l = P.layer;

  __shared__ float qs[128];
  __shared__ float qwe_s[64];
  __shared__ float qbe_s[8];
  __shared__ float es[8*PS];
  __shared__ float ps[8*PS];
  __shared__ float red_s[32];
  __shared__ float ssum_s[8];
  __shared__ float g_s[64];
  __shared__ float res_s[128];
  __shared__ float red_a[2], red_b[2], red_c[2];

  if (t < 128) qs[t] = P.q[(b*NN+i)*DMM + t];
  __syncthreads();
  if (t < 64){
    const int h = t>>3, c = t&7;
    const float* Wer = P.We + l*DEE*DMM + c*DMM + h*DD;
    float a = 0.f;
    #pragma unroll
    for (int d=0; d<DD; d++) a += qs[h*DD+d]*Wer[d];
    qwe_s[t] = a;
    if (c==0){
      const float* ber = P.be + l*DMM + h*DD;
      float a2 = 0.f;
      #pragma unroll
      for (int d=0; d<DD; d++) a2 += qs[h*DD+d]*ber[d];
      qbe_s[h] = a2;
    }
  }
  __syncthreads();

  {
    const int j = t;
    const float4* er4 = (const float4*)(P.edges + ((size_t)(b*NN+i)*NN + j)*DEE);
    float4 e0 = er4[0], e1 = er4[1];
    float ec[8] = {e0.x,e0.y,e0.z,e0.w, e1.x,e1.y,e1.z,e1.w};
    #pragma unroll
    for (int c=0;c<8;c++) es[c*PS+j] = ec[c];
    const float adj = P.adjacency[(size_t)(b*NN+i)*NN + j];
    const float* kTj = P.k + (size_t)b*DMM*NN + j;   // column j of K^T panel
    float preg[8];
    #pragma unroll
    for (int h=0; h<HH; h++){
      const float* kc = kTj + (size_t)(h*DD)*NN;
      float sim = qbe_s[h];
      #pragma unroll
      for (int d=0; d<DD; d++) sim += qs[h*DD+d] * kc[(size_t)d*NN];
      const float4* qw4 = (const float4*)(qwe_s + h*8);
      float4 wA = qw4[0], wB = qw4[1];
      sim += ec[0]*wA.x + ec[1]*wA.y + ec[2]*wA.z + ec[3]*wA.w;
      sim += ec[4]*wB.x + ec[5]*wB.y + ec[6]*wB.z + ec[7]*wB.w;
      sim *= SCALE;
      float p = __expf(sim) * adj;
      preg[h] = p;
      ps[h*PS+j] = p;
    }
    #pragma unroll
    for (int h=0; h<HH; h++){
      float v = preg[h];
      #pragma unroll
      for (int off=32; off; off>>=1) v += __shfl_xor(v, off, 64);
      if ((t&63)==0) red_s[(t>>6)*8 + h] = v;
    }
  }
  __syncthreads();

  float pv = 0.f;
  if (t < 128){
    const int h = t>>4;
    const float* vcol = P.v + b*NN*DMM + t;
    const float4* pr = (const float4*)(ps + h*PS);
    #pragma unroll 4
    for (int jq=0; jq<64; jq++){
      float4 pp = pr[jq];
      const float* vv = vcol + jq*4*DMM;
      pv += pp.x*vv[0] + pp.y*vv[DMM] + pp.z*vv[2*DMM] + pp.w*vv[3*DMM];
    }
  } else if (t < 192){
    const int h = (t-128)>>3, c = (t-128)&7;
    const float4* pr = (const float4*)(ps + h*PS);
    const float4* er = (const float4*)(es + c*PS);
    float g = 0.f;
    #pragma unroll 4
    for (int jq=0; jq<64; jq++){
      float4 pp = pr[jq], ee = er[jq];
      g += pp.x*ee.x + pp.y*ee.y + pp.z*ee.z + pp.w*ee.w;
    }
    g_s[h*8+c] = g;
  } else {
    const int u = t - 192;
    const float2 rv = *(const float2*)(P.res + (b*NN+i)*DMM + 2*u);
    res_s[2*u] = rv.x; res_s[2*u+1] = rv.y;
    if (t >= 248){
      const int h = t - 248;
      ssum_s[h] = red_s[h] + red_s[8+h] + red_s[16+h] + red_s[24+h];
    }
  }
  __syncthreads();

  float o = 0.f, rr = 0.f;
  if (t < 128){
    const int h = t>>4;
    const float* Wec = P.We + l*DEE*DMM + t;
    float eacc = 0.f;
    #pragma unroll
    for (int c=0;c<8;c++) eacc += Wec[c*DMM] * g_s[h*8+c];
    const float ssum = ssum_s[h];
    const float denom = (ssum==0.f) ? 1.f : ssum;
    const float bev = P.be[l*DMM + t];
    o = (pv + eacc + ssum*bev) / denom;
    rr = res_s[t];
    const float* Wg = P.Wgate + l*3*DMM;
    float contrib = o*Wg[t] + rr*Wg[DMM+t] + (o-rr)*Wg[2*DMM+t];
    #pragma unroll
    for (int off=32; off; off>>=1) contrib += __shfl_xor(contrib, off, 64);
    if ((t&63)==0) red_a[t>>6] = contrib;
  }
  __syncthreads();

  float y = 0.f;
  if (t < 128){
    const float gs = red_a[0] + red_a[1];
    const float gate = 1.f/(1.f + __expf(-gs));
    y = o*gate + rr*(1.f-gate);
    float s1 = y, s2 = y*y;
    #pragma unroll
    for (int off=32; off; off>>=1){ s1 += __shfl_xor(s1, off, 64); s2 += __shfl_xor(s2, off, 64); }
    if ((t&63)==0){ red_b[t>>6] = s1; red_c[t>>6] = s2; }
  }
  __syncthreads();

  if (t < 128){
    const float mu  = (red_b[0]+red_b[1]) * (1.f/128.f);
    const float var = (red_c[0]+red_c[1]) * (1.f/128.f) - mu*mu;
    const float inv = rsqrtf(var + 1e-5f);
    float yn = (y - mu)*inv*P.lng[l*DMM+t] + P.lnb[l*DMM+t];
    yn = fmaxf(yn, 0.f);
    P.out[(b*NN+i)*DMM + t] = yn;
  }
}

extern "C" void kernel_launch(void* const* d_in, const int* in_sizes, int n_in,
                              void* d_out, int out_size, void* d_ws, size_t ws_size,
                              hipStream_t stream) {
  Params P;
  P.nodes     = (const float*)d_in[0];
  P.edges     = (const float*)d_in[1];
  P.adjacency = (const float*)d_in[2];
  P.Wq   = (const float*)d_in[3];  P.bq   = (const float*)d_in[4];
  P.Wk   = (const float*)d_in[5];  P.bk   = (const float*)d_in[6];
  P.Wv   = (const float*)d_in[7];  P.bv   = (const float*)d_in[8];
  P.We   = (const float*)d_in[9];  P.be   = (const float*)d_in[10];
  P.Wres = (const float*)d_in[11]; P.bres = (const float*)d_in[12];
  P.Wgate= (const float*)d_in[13];
  P.lng  = (const float*)d_in[14]; P.lnb  = (const float*)d_in[15];

  float* f = (float*)d_ws;
  // per-layer buffers: [2][SS] each
  float* qbuf = f;            // q0 at +0, q1 at +SS
  float* kbuf = f + 2*SS;     // TRANSPOSED [b][d][j]
  float* vbuf = f + 4*SS;
  float* rbuf = f + 6*SS;
  P.out = (float*)d_out;

  // D1: proj layer 0 (512 blocks x 2 rows)
  P.layer = 0; P.src = P.nodes;
  P.q = qbuf; P.k = kbuf; P.v = vbuf; P.res = rbuf;
  hipLaunchKernelGGL(k_proj, dim3(BB*NN/2), dim3(256), 0, stream, P);

  // D2: attn(l0, 2 concurrent rows) + proj(l1)
  hipLaunchKernelGGL(k_mid, dim3(BB*NN/2), dim3(512), 0, stream, P);

  // D3: attn(l1) -> out
  P.layer = 1;
  P.q = qbuf + SS; P.k = kbuf + SS; P.v = vbuf + SS; P.res = rbuf + SS;
  hipLaunchKernelGGL(k_attn, dim3(BB*NN), dim3(256), 0, stream, P);
}